// Round 2
// baseline (273.389 us; speedup 1.0000x reference)
//
#include <hip/hip_runtime.h>
#include <hip/hip_bf16.h>

#define B_ 8
#define L_ 2048
#define D_ 128
#define SCALE 0.08838834764831845f  // 1/sqrt(128)

typedef __attribute__((ext_vector_type(8))) short short8;  // 8 bf16 = 4 VGPR (MFMA A/B frag)
typedef __attribute__((ext_vector_type(4))) short s16x4;   // 4 bf16 = 8B LDS write
typedef __attribute__((ext_vector_type(4))) float f32x4;   // MFMA C/D frag

// Device-global scratch (fully rewritten every call).
__device__ float          g_lpart[2 * B_ * L_];        // rowsum partials [jhalf][b*L+i]
__device__ unsigned short g_vT[(size_t)B_ * D_ * L_];  // v^T as bf16: [b][d][i]
__device__ unsigned short g_qb[(size_t)B_ * L_ * D_];  // q as bf16 rows
__device__ unsigned short g_vb[(size_t)B_ * L_ * D_];  // v as bf16 rows

static __device__ __forceinline__ float4 ld4(const float* p) { return *(const float4*)p; }
static __device__ __forceinline__ short bf(float f) {
    union { __hip_bfloat16 h; short s; } u; u.h = __float2bfloat16(f); return u.s;
}
static __device__ __forceinline__ short8 pack8(float4 a, float4 b) {
    short8 r;
    r[0] = bf(a.x); r[1] = bf(a.y); r[2] = bf(a.z); r[3] = bf(a.w);
    r[4] = bf(b.x); r[5] = bf(b.y); r[6] = bf(b.z); r[7] = bf(b.w);
    return r;
}
static __device__ __forceinline__ f32x4 mfma16(short8 a, short8 b, f32x4 c) {
    return __builtin_amdgcn_mfma_f32_16x16x32_bf16(a, b, c, 0, 0, 0);
}

// Kc: bf16 row copies of q and v (one-time convert; hot loops then do pure short8 moves).
// 2048 blocks x 256 thr; first 1024 handle q -> g_qb, rest v -> g_vb. 8 floats/thread.
__global__ __launch_bounds__(256) void cvt_kernel(const float* __restrict__ q,
                                                  const float* __restrict__ v) {
    const bool isq = blockIdx.x < 1024;
    const size_t idx = ((size_t)(isq ? blockIdx.x : blockIdx.x - 1024) * 256 + threadIdx.x) * 8;
    const float* p = (isq ? q : v) + idx;
    *(short8*)(void*)((isq ? g_qb : g_vb) + idx) = pack8(ld4(p), ld4(p + 4));
}

// K0: g_vT[b][d][i] = bf16(v[b][i][d]).  256 blocks x 256 thr, 64i x 128d tiles.
__global__ __launch_bounds__(256) void vT_kernel(const float* __restrict__ v) {
    __shared__ float t[64 * 132];  // [i][d], pitch 132
    const int tid = threadIdx.x;
    const int b = blockIdx.x >> 5, i0 = (blockIdx.x & 31) * 64;
    const float* vb = v + ((size_t)b * L_ + i0) * D_;
    #pragma unroll
    for (int c = 0; c < 8; ++c) {
        const int g = c * 256 + tid, row = g >> 5, c4 = (g & 31) * 4;
        *(float4*)(t + row * 132 + c4) = ld4(vb + (size_t)row * D_ + c4);
    }
    __syncthreads();
    #pragma unroll
    for (int c = 0; c < 4; ++c) {
        const int g = c * 256 + tid, d = g >> 3, i8 = (g & 7) * 8;
        short8 r;
        #pragma unroll
        for (int j = 0; j < 8; ++j) r[j] = bf(t[(i8 + j) * 132 + d]);
        *(short8*)(void*)(g_vT + ((size_t)b * D_ + d) * L_ + i0 + i8) = r;
    }
}

// Pass A: l[i] partials only (K1 minus the attn store). Grid: b x 32 it x 2 jh = 512,
// b = blockIdx&7 so same-b blocks share an XCD L2 (v_b re-reads stay local).
__global__ __launch_bounds__(256) void lsum_kernel() {
    __shared__ short vs[64 * 136];  // bf16 v rows [j_local][k], pitch 136
    const int tid = threadIdx.x;
    const int b = blockIdx.x & 7, rest = blockIdx.x >> 3;
    const int it = rest & 31, jh = rest >> 5;
    const int i0 = it * 64;
    const int w = tid >> 6, lid = tid & 63, n16 = lid & 15, quad = lid >> 4;

    short8 qa[4];
    const unsigned short* qrow = g_qb + ((size_t)b * L_ + i0 + w * 16 + n16) * D_ + quad * 8;
    #pragma unroll
    for (int c = 0; c < 4; ++c) qa[c] = *(const short8*)(qrow + c * 32);

    float racc[4] = {0.f, 0.f, 0.f, 0.f};
    const unsigned short* vbp = g_vb + (size_t)b * L_ * D_;

    for (int jt = 0; jt < 16; ++jt) {
        const int jb = jh * 1024 + jt * 64;
        __syncthreads();
        #pragma unroll
        for (int c = 0; c < 4; ++c) {  // stage 64 bf16 v rows (pure copy)
            const int g = c * 256 + tid, row = g >> 4, col8 = (g & 15) * 8;
            *(short8*)(vs + row * 136 + col8) =
                *(const short8*)(vbp + (size_t)(jb + row) * D_ + col8);
        }
        __syncthreads();
        #pragma unroll
        for (int jc = 0; jc < 4; ++jc) {
            f32x4 d = {0.f, 0.f, 0.f, 0.f};
            #pragma unroll
            for (int c = 0; c < 4; ++c) {
                const short8 vf = *(const short8*)(vs + (jc * 16 + n16) * 136 + c * 32 + quad * 8);
                d = mfma16(qa[c], vf, d);
            }
            #pragma unroll
            for (int r = 0; r < 4; ++r) racc[r] += __expf(d[r] * SCALE);
        }
    }
    #pragma unroll
    for (int m = 1; m <= 8; m <<= 1)
        #pragma unroll
        for (int r = 0; r < 4; ++r) racc[r] += __shfl_xor(racc[r], m, 64);
    if (n16 == 0) {
        *(float4*)(g_lpart + jh * (B_ * L_) + b * L_ + i0 + w * 16 + quad * 4) =
            make_float4(racc[0], racc[1], racc[2], racc[3]);
    }
}

// Pass B: recompute scores, normalize with 1/(l0+l1), write attn (single mandatory
// 128MB write) AND feed bf16 through LDS into PV GEMM: out[b,j,d]=sum_i attn[i][j]v[i][d].
// Grid: b(blockIdx&7) x 64 j-slabs(32) = 512. Waves: phase1 w owns i-rows w*16..+15;
// phase2 jg=w&1 (16 j), dgrp=w>>1 (64 d) — identical to verified K3 layouts.
__global__ __launch_bounds__(256) void fused_kernel(float* __restrict__ attn,
                                                    float* __restrict__ out) {
    __shared__ short vj[32 * 136];  // v rows j0..j0+31 bf16 [j_local][d] (resident)
    __shared__ short aT[32 * 72];   // [j_local][i_local], pitch 72
    __shared__ short vT[128 * 72];  // [d][i_local], pitch 72
    const int tid = threadIdx.x;
    const int b = blockIdx.x & 7, j0 = (blockIdx.x >> 3) * 32;
    const int w = tid >> 6, lid = tid & 63, n16 = lid & 15, quad = lid >> 4;
    const int jg = w & 1, dgrp = w >> 1;
    float* ab = attn + (size_t)b * L_ * L_;
    const unsigned short* vTb = g_vT + (size_t)b * D_ * L_;
    const unsigned short* qbb = g_qb + (size_t)b * L_ * D_;
    const unsigned short* vbp = g_vb + (size_t)b * L_ * D_;
    const float* lp0 = g_lpart + (size_t)b * L_;
    const float* lp1 = g_lpart + (size_t)(B_ * L_) + (size_t)b * L_;

    #pragma unroll
    for (int c = 0; c < 2; ++c) {  // stage vj once (32 rows)
        const int g = c * 256 + tid, row = g >> 4, col8 = (g & 15) * 8;
        *(short8*)(vj + row * 136 + col8) =
            *(const short8*)(vbp + (size_t)(j0 + row) * D_ + col8);
    }

    f32x4 oacc[4];
    #pragma unroll
    for (int dc = 0; dc < 4; ++dc) oacc[dc] = (f32x4){0.f, 0.f, 0.f, 0.f};

    for (int i0 = 0; i0 < L_; i0 += 64) {
        __syncthreads();  // aT/vT safe to overwrite; first iter: vj staged
        // phase 1: scores rows i0+w*16..+15 x 32 j, normalize, store attn + aT
        short8 qa[4];
        const unsigned short* qrow = qbb + (size_t)(i0 + w * 16 + n16) * D_ + quad * 8;
        #pragma unroll
        for (int c = 0; c < 4; ++c) qa[c] = *(const short8*)(qrow + c * 32);
        const float4 s0 = ld4(lp0 + i0 + w * 16 + quad * 4);
        const float4 s1 = ld4(lp1 + i0 + w * 16 + quad * 4);
        const float linv[4] = {1.0f / (s0.x + s1.x), 1.0f / (s0.y + s1.y),
                               1.0f / (s0.z + s1.z), 1.0f / (s0.w + s1.w)};
        #pragma unroll
        for (int jc = 0; jc < 2; ++jc) {
            f32x4 d = {0.f, 0.f, 0.f, 0.f};
            #pragma unroll
            for (int c = 0; c < 4; ++c) {
                const short8 vf = *(const short8*)(vj + (jc * 16 + n16) * 136 + c * 32 + quad * 8);
                d = mfma16(qa[c], vf, d);
            }
            float* ap = ab + (size_t)(i0 + w * 16 + quad * 4) * L_ + j0 + jc * 16 + n16;
            s16x4 aw;
            #pragma unroll
            for (int r = 0; r < 4; ++r) {
                const float e = __expf(d[r] * SCALE) * linv[r];
                ap[(size_t)r * L_] = e;
                aw[r] = bf(e);
            }
            *(s16x4*)(aT + (jc * 16 + n16) * 72 + w * 16 + quad * 4) = aw;
        }
        #pragma unroll
        for (int c = 0; c < 4; ++c) {  // stage vT tile [128 d][64 i]
            const int g = c * 256 + tid, dd = g >> 3, ic = (g & 7) * 8;
            *(short8*)(vT + dd * 72 + ic) =
                *(const short8*)(vTb + (size_t)dd * L_ + i0 + ic);
        }
        __syncthreads();
        // phase 2: PV accumulate
        #pragma unroll
        for (int kc = 0; kc < 2; ++kc) {
            const short8 af = *(const short8*)(aT + (jg * 16 + n16) * 72 + kc * 32 + quad * 8);
            #pragma unroll
            for (int dc = 0; dc < 4; ++dc) {
                const short8 vf = *(const short8*)(
                    vT + (dgrp * 64 + dc * 16 + n16) * 72 + kc * 32 + quad * 8);
                oacc[dc] = mfma16(af, vf, oacc[dc]);
            }
        }
    }
    // D[row=j_local=quad*4+r][col=d=n16] per dc chunk
    #pragma unroll
    for (int dc = 0; dc < 4; ++dc)
        #pragma unroll
        for (int r = 0; r < 4; ++r)
            out[((size_t)b * L_ + j0 + jg * 16 + quad * 4 + r) * D_ + dgrp * 64 + dc * 16 + n16] =
                oacc[dc][r];
}

extern "C" void kernel_launch(void* const* d_in, const int* in_sizes, int n_in,
                              void* d_out, int out_size, void* d_ws, size_t ws_size,
                              hipStream_t stream) {
    const float* q = (const float*)d_in[0];
    // d_in[1] = k: unused by the reference (scores come from q and v).
    const float* v = (const float*)d_in[2];
    float* out  = (float*)d_out;
    float* attn = out + (size_t)B_ * L_ * D_;  // outputs concatenated: [out | attn]

    cvt_kernel<<<dim3(2048), 256, 0, stream>>>(q, v);
    vT_kernel<<<dim3(B_ * 32), 256, 0, stream>>>(v);
    lsum_kernel<<<dim3(B_ * 64), 256, 0, stream>>>();
    fused_kernel<<<dim3(B_ * 64), 256, 0, stream>>>(attn, out);

    (void)in_sizes; (void)n_in; (void)out_size; (void)d_ws; (void)ws_size;
}

// Round 3
// 258.406 us; speedup vs baseline: 1.0580x; 1.0580x over previous
//
#include <hip/hip_runtime.h>
#include <hip/hip_bf16.h>

#define B_ 8
#define L_ 2048
#define D_ 128
#define SCALE 0.08838834764831845f  // 1/sqrt(128)

typedef __attribute__((ext_vector_type(8))) short short8;  // 8 bf16 = 4 VGPR (MFMA A/B frag)
typedef __attribute__((ext_vector_type(4))) short s16x4;   // 4 bf16 = 8B LDS write
typedef __attribute__((ext_vector_type(4))) float f32x4;   // MFMA C/D frag

// Device-global scratch (fully rewritten every call).
__device__ float          g_lpart[2 * B_ * L_];        // rowsum partials [jhalf][b*L+i]
__device__ unsigned short g_vT[(size_t)B_ * D_ * L_];  // v^T bf16, layout [b][i/32][d][i%32]
__device__ unsigned short g_qb[(size_t)B_ * L_ * D_];  // q as bf16 rows
__device__ unsigned short g_vb[(size_t)B_ * L_ * D_];  // v as bf16 rows

static __device__ __forceinline__ float4 ld4(const float* p) { return *(const float4*)p; }
static __device__ __forceinline__ short bf(float f) {
    union { __hip_bfloat16 h; short s; } u; u.h = __float2bfloat16(f); return u.s;
}
static __device__ __forceinline__ short8 pack8(float4 a, float4 b) {
    short8 r;
    r[0] = bf(a.x); r[1] = bf(a.y); r[2] = bf(a.z); r[3] = bf(a.w);
    r[4] = bf(b.x); r[5] = bf(b.y); r[6] = bf(b.z); r[7] = bf(b.w);
    return r;
}
static __device__ __forceinline__ f32x4 mfma16(short8 a, short8 b, f32x4 c) {
    return __builtin_amdgcn_mfma_f32_16x16x32_bf16(a, b, c, 0, 0, 0);
}

// Kc: q -> g_qb bf16 rows. 1024 blocks x 256 thr, 8 floats/thread.
__global__ __launch_bounds__(256) void cvt_q_kernel(const float* __restrict__ q) {
    const size_t idx = ((size_t)blockIdx.x * 256 + threadIdx.x) * 8;
    *(short8*)(void*)(g_qb + idx) = pack8(ld4(q + idx), ld4(q + idx + 4));
}

// K0: v -> g_vT ([b][i/32][d][i%32], so PV frag loads are wave-contiguous 1KB)
//     AND g_vb (bf16 rows).  256 blocks x 256 thr, 64i x 128d tiles.
__global__ __launch_bounds__(256) void vT_kernel(const float* __restrict__ v) {
    __shared__ float t[64 * 132];  // [i][d], pitch 132
    const int tid = threadIdx.x;
    const int b = blockIdx.x >> 5, i0 = (blockIdx.x & 31) * 64;
    const float* vb = v + ((size_t)b * L_ + i0) * D_;
    #pragma unroll
    for (int c = 0; c < 8; ++c) {
        const int g = c * 256 + tid, row = g >> 5, c4 = (g & 31) * 4;
        *(float4*)(t + row * 132 + c4) = ld4(vb + (size_t)row * D_ + c4);
    }
    __syncthreads();
    #pragma unroll
    for (int c = 0; c < 4; ++c) {  // transposed store, [b][ic][d][ioff]
        const int g = c * 256 + tid, d = g >> 3, i8 = (g & 7) * 8;
        short8 r;
        #pragma unroll
        for (int j = 0; j < 8; ++j) r[j] = bf(t[(i8 + j) * 132 + d]);
        const int ic = (i0 + i8) >> 5, ioff = (i0 + i8) & 31;
        *(short8*)(void*)(g_vT + (((size_t)b * 64 + ic) * 128 + d) * 32 + ioff) = r;
    }
    #pragma unroll
    for (int c = 0; c < 4; ++c) {  // row-major bf16 rows from same staged tile
        const int g = c * 256 + tid, row = g >> 4, cc = g & 15;
        short8 r;
        #pragma unroll
        for (int j = 0; j < 8; ++j) r[j] = bf(t[row * 132 + cc * 8 + j]);
        *(short8*)(void*)(g_vb + ((size_t)b * L_ + i0 + row) * D_ + cc * 8) = r;
    }
}

// Pass A: row sums l[i].  Grid b(&7) x 32 it x 2 jh = 512.  Double-buffered
// XOR-swizzled LDS staging, ONE barrier per 64-j tile.
__global__ __launch_bounds__(256) void lsum_kernel() {
    __shared__ short vs[2][64 * 128];  // bf16 v rows, unpadded, 16B-chunk XOR swizzle
    const int tid = threadIdx.x;
    const int b = blockIdx.x & 7, rest = blockIdx.x >> 3;
    const int it = rest & 31, jh = rest >> 5;
    const int i0 = it * 64;
    const int w = tid >> 6, lid = tid & 63, n16 = lid & 15, quad = lid >> 4;
    const int r8 = n16 & 7;

    short8 qa[4];
    const unsigned short* qrow = g_qb + ((size_t)b * L_ + i0 + w * 16 + n16) * D_ + quad * 8;
    #pragma unroll
    for (int c = 0; c < 4; ++c) qa[c] = *(const short8*)(qrow + c * 32);

    const unsigned short* vbp = g_vb + ((size_t)b * L_ + (size_t)jh * 1024) * D_;
    #pragma unroll
    for (int c = 0; c < 4; ++c) {  // prologue: stage jt=0 into vs[0]
        const int g = c * 256 + tid, row = g >> 4, cc = g & 15;
        *(short8*)(&vs[0][row * 128 + ((cc ^ (row & 7)) * 8)]) =
            *(const short8*)(vbp + (size_t)row * D_ + cc * 8);
    }

    float racc[4] = {0.f, 0.f, 0.f, 0.f};
    int p = 0;
    for (int jt = 0; jt < 16; ++jt) {
        __syncthreads();  // vs[p] staged; all prior reads of vs[p^1] complete
        if (jt < 15) {    // stage next tile into the other buffer
            const unsigned short* src = vbp + (size_t)(jt + 1) * 64 * D_;
            #pragma unroll
            for (int c = 0; c < 4; ++c) {
                const int g = c * 256 + tid, row = g >> 4, cc = g & 15;
                *(short8*)(&vs[p ^ 1][row * 128 + ((cc ^ (row & 7)) * 8)]) =
                    *(const short8*)(src + (size_t)row * D_ + cc * 8);
            }
        }
        const short* vsp = vs[p];
        #pragma unroll
        for (int jc = 0; jc < 4; ++jc) {
            f32x4 d = {0.f, 0.f, 0.f, 0.f};
            #pragma unroll
            for (int c = 0; c < 4; ++c) {
                const short8 vf = *(const short8*)(
                    vsp + (jc * 16 + n16) * 128 + (((c * 4 + quad) ^ r8) * 8));
                d = mfma16(qa[c], vf, d);
            }
            #pragma unroll
            for (int r = 0; r < 4; ++r) racc[r] += __expf(d[r] * SCALE);
        }
        p ^= 1;
    }
    #pragma unroll
    for (int m = 1; m <= 8; m <<= 1)
        #pragma unroll
        for (int r = 0; r < 4; ++r) racc[r] += __shfl_xor(racc[r], m, 64);
    if (n16 == 0) {
        *(float4*)(g_lpart + jh * (B_ * L_) + b * L_ + i0 + w * 16 + quad * 4) =
            make_float4(racc[0], racc[1], racc[2], racc[3]);
    }
}

// Pass B: recompute scores, normalize by 1/(l0+l1), write attn fp32 (the single
// mandatory 128MB write) and feed bf16 into PV via tiny double-buffered aT LDS.
// PV B-frags read DIRECT from g_vT (zero reuse -> no LDS round trip; coalesced 1KB).
// Grid: b(&7) x 128 j-slabs(16) = 1024 blocks (4/CU), 4 waves, ONE barrier/i-tile.
__global__ __launch_bounds__(256) void fused_kernel(float* __restrict__ attn,
                                                    float* __restrict__ out) {
    __shared__ short vj[16 * 128];     // v rows j0..j0+15, XOR-swizzled (static)
    __shared__ short aT[2][16 * 64];   // attn^T handoff [j][i], XOR-swizzled, dbuf
    const int tid = threadIdx.x;
    const int b = blockIdx.x & 7, j0 = (blockIdx.x >> 3) * 16;
    const int w = tid >> 6, lid = tid & 63, n16 = lid & 15, quad = lid >> 4;
    const int r8 = n16 & 7;
    float* ab = attn + (size_t)b * L_ * L_;
    const unsigned short* vT2b = g_vT + (size_t)b * 64 * 128 * 32;
    const unsigned short* qbb = g_qb + (size_t)b * L_ * D_;
    const unsigned short* vbp = g_vb + (size_t)b * L_ * D_;
    const float* lp0 = g_lpart + (size_t)b * L_;
    const float* lp1 = g_lpart + (size_t)(B_ * L_) + (size_t)b * L_;

    {   // stage vj once: 256 chunks, 1/thread
        const int row = tid >> 4, cc = tid & 15;
        *(short8*)(&vj[row * 128 + ((cc ^ (row & 7)) * 8)]) =
            *(const short8*)(vbp + (size_t)(j0 + row) * D_ + cc * 8);
    }
    // prefetch t=0 q-frags + l-partials
    short8 qa[4];
    {
        const unsigned short* qrow = qbb + (size_t)(w * 16 + n16) * D_ + quad * 8;
        #pragma unroll
        for (int c = 0; c < 4; ++c) qa[c] = *(const short8*)(qrow + c * 32);
    }
    float4 s0 = ld4(lp0 + w * 16 + quad * 4);
    float4 s1 = ld4(lp1 + w * 16 + quad * 4);

    f32x4 oacc[2];
    oacc[0] = (f32x4){0.f, 0.f, 0.f, 0.f};
    oacc[1] = (f32x4){0.f, 0.f, 0.f, 0.f};
    __syncthreads();  // vj ready

    for (int t = 0; t < 32; ++t) {
        const int i0 = t * 64;
        // phase 1: 16i x 16j scores for this wave's rows
        f32x4 d = {0.f, 0.f, 0.f, 0.f};
        #pragma unroll
        for (int c = 0; c < 4; ++c) {
            const short8 vf = *(const short8*)(&vj[n16 * 128 + (((c * 4 + quad) ^ r8) * 8)]);
            d = mfma16(qa[c], vf, d);
        }
        const float linv[4] = {1.0f / (s0.x + s1.x), 1.0f / (s0.y + s1.y),
                               1.0f / (s0.z + s1.z), 1.0f / (s0.w + s1.w)};
        float* ap = ab + (size_t)(i0 + w * 16 + quad * 4) * L_ + j0 + n16;
        s16x4 aw;
        #pragma unroll
        for (int r = 0; r < 4; ++r) {
            const float e = __expf(d[r] * SCALE) * linv[r];
            ap[(size_t)r * L_] = e;
            aw[r] = bf(e);
        }
        {   // aT[t&1] write: logical i-chunk8 = w*2+(quad>>1), XOR-swizzled by j&7
            const int ch = w * 2 + (quad >> 1);
            *(s16x4*)(&aT[t & 1][n16 * 64 + ((ch ^ r8) * 8) + (quad & 1) * 4]) = aw;
        }
        if (t < 31) {  // prefetch next iter's q-frags + l-partials (hidden by phase2)
            const unsigned short* qrow = qbb + (size_t)(i0 + 64 + w * 16 + n16) * D_ + quad * 8;
            #pragma unroll
            for (int c = 0; c < 4; ++c) qa[c] = *(const short8*)(qrow + c * 32);
            s0 = ld4(lp0 + i0 + 64 + w * 16 + quad * 4);
            s1 = ld4(lp1 + i0 + 64 + w * 16 + quad * 4);
        }
        // PV B-frags direct from global (coalesced 1KB/wave-load), issued pre-barrier
        short8 vfr[2][2];
        #pragma unroll
        for (int dc = 0; dc < 2; ++dc)
            #pragma unroll
            for (int kc = 0; kc < 2; ++kc)
                vfr[dc][kc] = *(const short8*)(
                    vT2b + ((size_t)(t * 2 + kc) * 128 + (w * 32 + dc * 16 + n16)) * 32 + quad * 8);
        __syncthreads();  // aT[t&1] complete (prior reads of other buffer already done)
        // phase 2: PV accumulate, A=attn^T[j][i], B=vT[d][i]
        #pragma unroll
        for (int kc = 0; kc < 2; ++kc) {
            const short8 af = *(const short8*)(
                &aT[t & 1][n16 * 64 + (((kc * 4 + quad) ^ r8) * 8)]);
            #pragma unroll
            for (int dc = 0; dc < 2; ++dc) oacc[dc] = mfma16(af, vfr[dc][kc], oacc[dc]);
        }
    }
    // D[row=j_local=quad*4+r][col=d=n16]; wave w owns d = w*32..w*32+31
    #pragma unroll
    for (int dc = 0; dc < 2; ++dc)
        #pragma unroll
        for (int r = 0; r < 4; ++r)
            out[((size_t)b * L_ + j0 + quad * 4 + r) * D_ + w * 32 + dc * 16 + n16] =
                oacc[dc][r];
}

extern "C" void kernel_launch(void* const* d_in, const int* in_sizes, int n_in,
                              void* d_out, int out_size, void* d_ws, size_t ws_size,
                              hipStream_t stream) {
    const float* q = (const float*)d_in[0];
    // d_in[1] = k: unused by the reference (scores come from q and v).
    const float* v = (const float*)d_in[2];
    float* out  = (float*)d_out;
    float* attn = out + (size_t)B_ * L_ * D_;  // outputs concatenated: [out | attn]

    cvt_q_kernel<<<dim3(1024), 256, 0, stream>>>(q);
    vT_kernel<<<dim3(B_ * 32), 256, 0, stream>>>(v);
    lsum_kernel<<<dim3(B_ * 64), 256, 0, stream>>>();
    fused_kernel<<<dim3(B_ * 128), 256, 0, stream>>>(attn, out);

    (void)in_sizes; (void)n_in; (void)out_size; (void)d_ws; (void)ws_size;
}

// Round 4
// 200.228 us; speedup vs baseline: 1.3654x; 1.2906x over previous
//
#include <hip/hip_runtime.h>
#include <hip/hip_bf16.h>

#define B_ 8
#define L_ 2048
#define D_ 128
#define SCALE 0.08838834764831845f  // 1/sqrt(128)

typedef __attribute__((ext_vector_type(8))) short short8;  // 8 bf16 = 4 VGPR (MFMA A/B frag)
typedef __attribute__((ext_vector_type(4))) short s16x4;   // 4 bf16 = 8B LDS write
typedef __attribute__((ext_vector_type(4))) float f32x4;   // MFMA C/D frag

// Device-global scratch (fully rewritten every call).
__device__ float          g_lpart[2 * B_ * L_];        // rowsum partials [jhalf][b*L+i]
__device__ unsigned short g_vT[(size_t)B_ * D_ * L_];  // v^T bf16, layout [b][i/32][d][i%32]
__device__ unsigned short g_qb[(size_t)B_ * L_ * D_];  // q as bf16 rows
__device__ unsigned short g_vb[(size_t)B_ * L_ * D_];  // v as bf16 rows

static __device__ __forceinline__ float4 ld4(const float* p) { return *(const float4*)p; }
static __device__ __forceinline__ short bf(float f) {
    union { __hip_bfloat16 h; short s; } u; u.h = __float2bfloat16(f); return u.s;
}
static __device__ __forceinline__ short8 pack8(float4 a, float4 b) {
    short8 r;
    r[0] = bf(a.x); r[1] = bf(a.y); r[2] = bf(a.z); r[3] = bf(a.w);
    r[4] = bf(b.x); r[5] = bf(b.y); r[6] = bf(b.z); r[7] = bf(b.w);
    return r;
}
static __device__ __forceinline__ f32x4 mfma16(short8 a, short8 b, f32x4 c) {
    return __builtin_amdgcn_mfma_f32_16x16x32_bf16(a, b, c, 0, 0, 0);
}

// Raw barrier: drain LDS ops only (NOT vmcnt) so global stores pipeline across
// iterations. sched_barrier(0) stops hipcc hoisting post-barrier LDS reads (rule #18).
#define BAR() do { asm volatile("s_waitcnt lgkmcnt(0)" ::: "memory"); \
                   __builtin_amdgcn_s_barrier();                      \
                   __builtin_amdgcn_sched_barrier(0); } while (0)

// Kc: q -> g_qb bf16 rows. 1024 blocks x 256 thr, 8 floats/thread.
__global__ __launch_bounds__(256) void cvt_q_kernel(const float* __restrict__ q) {
    const size_t idx = ((size_t)blockIdx.x * 256 + threadIdx.x) * 8;
    *(short8*)(void*)(g_qb + idx) = pack8(ld4(q + idx), ld4(q + idx + 4));
}

// K0: v -> g_vT ([b][i/32][d][i%32]) AND g_vb (bf16 rows). 256 blocks x 256 thr.
__global__ __launch_bounds__(256) void vT_kernel(const float* __restrict__ v) {
    __shared__ float t[64 * 132];  // [i][d], pitch 132
    const int tid = threadIdx.x;
    const int b = blockIdx.x >> 5, i0 = (blockIdx.x & 31) * 64;
    const float* vb = v + ((size_t)b * L_ + i0) * D_;
    #pragma unroll
    for (int c = 0; c < 8; ++c) {
        const int g = c * 256 + tid, row = g >> 5, c4 = (g & 31) * 4;
        *(float4*)(t + row * 132 + c4) = ld4(vb + (size_t)row * D_ + c4);
    }
    __syncthreads();
    #pragma unroll
    for (int c = 0; c < 4; ++c) {  // transposed store, [b][ic][d][ioff]
        const int g = c * 256 + tid, d = g >> 3, i8 = (g & 7) * 8;
        short8 r;
        #pragma unroll
        for (int j = 0; j < 8; ++j) r[j] = bf(t[(i8 + j) * 132 + d]);
        const int ic = (i0 + i8) >> 5, ioff = (i0 + i8) & 31;
        *(short8*)(void*)(g_vT + (((size_t)b * 64 + ic) * 128 + d) * 32 + ioff) = r;
    }
    #pragma unroll
    for (int c = 0; c < 4; ++c) {  // row-major bf16 rows from same staged tile
        const int g = c * 256 + tid, row = g >> 4, cc = g & 15;
        short8 r;
        #pragma unroll
        for (int j = 0; j < 8; ++j) r[j] = bf(t[row * 132 + cc * 8 + j]);
        *(short8*)(void*)(g_vb + ((size_t)b * L_ + i0 + row) * D_ + cc * 8) = r;
    }
}

// Pass A: row sums l[i].  Grid b(&7) x 32 it x 2 jh = 512.  Reg-staged double
// buffer (T14): global loads for tile t+1 stay in flight across the raw barrier.
__global__ __launch_bounds__(256) void lsum_kernel() {
    __shared__ short vs[2][64 * 128];  // bf16 v rows, 16B-chunk XOR swizzle
    const int tid = threadIdx.x;
    const int b = blockIdx.x & 7, rest = blockIdx.x >> 3;
    const int it = rest & 31, jh = rest >> 5;
    const int i0 = it * 64;
    const int w = tid >> 6, lid = tid & 63, n16 = lid & 15, quad = lid >> 4;
    const int r8 = n16 & 7;
    const int srow = tid >> 4, scc = tid & 15;  // staging coords (4 chunks: +16 rows each? no: c*256)

    short8 qa[4];
    const unsigned short* qrow = g_qb + ((size_t)b * L_ + i0 + w * 16 + n16) * D_ + quad * 8;
    #pragma unroll
    for (int c = 0; c < 4; ++c) qa[c] = *(const short8*)(qrow + c * 32);

    const unsigned short* vbp = g_vb + ((size_t)b * L_ + (size_t)jh * 1024) * D_;
    short8 R[4];
    #pragma unroll
    for (int c = 0; c < 4; ++c) {  // prologue: load jt=0 tile to regs
        const int row = srow + c * 16;
        R[c] = *(const short8*)(vbp + (size_t)row * D_ + scc * 8);
    }

    float racc[4] = {0.f, 0.f, 0.f, 0.f};
    #pragma unroll
    for (int jt = 0; jt < 16; ++jt) {
        short* vsp = vs[jt & 1];
        #pragma unroll
        for (int c = 0; c < 4; ++c) {  // regs -> LDS (swizzled)
            const int row = srow + c * 16;
            *(short8*)(&vsp[row * 128 + ((scc ^ (row & 7)) * 8)]) = R[c];
        }
        if (jt < 15) {  // prefetch next tile to regs (crosses the barrier)
            const unsigned short* src = vbp + (size_t)(jt + 1) * 64 * D_;
            #pragma unroll
            for (int c = 0; c < 4; ++c) {
                const int row = srow + c * 16;
                R[c] = *(const short8*)(src + (size_t)row * D_ + scc * 8);
            }
        }
        BAR();
        #pragma unroll
        for (int jc = 0; jc < 4; ++jc) {
            f32x4 d = {0.f, 0.f, 0.f, 0.f};
            #pragma unroll
            for (int c = 0; c < 4; ++c) {
                const short8 vf = *(const short8*)(
                    &vsp[(jc * 16 + n16) * 128 + (((c * 4 + quad) ^ r8) * 8)]);
                d = mfma16(qa[c], vf, d);
            }
            #pragma unroll
            for (int r = 0; r < 4; ++r) racc[r] += __expf(d[r] * SCALE);
        }
    }
    #pragma unroll
    for (int m = 1; m <= 8; m <<= 1)
        #pragma unroll
        for (int r = 0; r < 4; ++r) racc[r] += __shfl_xor(racc[r], m, 64);
    if (n16 == 0) {
        *(float4*)(g_lpart + jh * (B_ * L_) + b * L_ + i0 + w * 16 + quad * 4) =
            make_float4(racc[0], racc[1], racc[2], racc[3]);
    }
}

// Pass B: per (b, 64-j slab): recompute scores, normalize, stage fp32 e in LDS,
// write attn in 256B row-runs (nontemporal), and PV-accumulate via bf16 aT tile.
// Grid 8b x 32 slabs = 256 blocks (1/CU), 512 thr (8 waves). i-tile = 128/iter,
// 16 iters, ONE raw barrier per iter; vf B-frags direct from g_vT (coalesced 1KB).
__global__ __launch_bounds__(512) void fused_kernel(float* __restrict__ attn,
                                                    float* __restrict__ out) {
    __shared__ short vj[64 * 128];     // v rows j0..j0+63 [j][k], swizzled (16KB)
    __shared__ float eF[2][128 * 64];  // fp32 e [i][j], chunk-swizzled (64KB)
    __shared__ short aT[2][64 * 128];  // bf16 attn^T [j][i], granule-swizzled (32KB)
    const int tid = threadIdx.x;
    const int b = blockIdx.x & 7, j0 = (blockIdx.x >> 3) * 64;
    const int w = tid >> 6, lid = tid & 63, n16 = lid & 15, quad = lid >> 4;
    const int r8 = n16 & 7;
    float* ab = attn + (size_t)b * L_ * L_;
    const unsigned short* vT2b = g_vT + (size_t)b * D_ * L_;
    const unsigned short* qbb = g_qb + (size_t)b * L_ * D_;
    const unsigned short* vbp = g_vb + (size_t)b * L_ * D_;
    const float* lp0 = g_lpart + (size_t)b * L_;
    const float* lp1 = g_lpart + (size_t)(B_ * L_) + (size_t)b * L_;

    #pragma unroll
    for (int c = 0; c < 2; ++c) {  // stage vj once: 1024 chunks of 16B
        const int g = c * 512 + tid, row = g >> 4, cc = g & 15;
        *(short8*)(&vj[row * 128 + ((cc ^ (row & 7)) * 8)]) =
            *(const short8*)(vbp + (size_t)(j0 + row) * D_ + cc * 8);
    }
    short8 qa[4];
    {
        const unsigned short* q0 = qbb + (size_t)(w * 16 + n16) * D_ + quad * 8;
        #pragma unroll
        for (int c = 0; c < 4; ++c) qa[c] = *(const short8*)(q0 + c * 32);
    }
    float4 s0 = ld4(lp0 + w * 16 + quad * 4);
    float4 s1 = ld4(lp1 + w * 16 + quad * 4);

    f32x4 oacc[4];
    #pragma unroll
    for (int jc = 0; jc < 4; ++jc) oacc[jc] = (f32x4){0.f, 0.f, 0.f, 0.f};
    __syncthreads();  // vj ready

    for (int t = 0; t < 16; ++t) {
        const int i0 = t * 128;
        float* eFp = eF[t & 1];
        short* aTp = aT[t & 1];
        // PV B-frags (issued FIRST so later vmcnt waits don't drain our stores)
        short8 vfr[4];
        #pragma unroll
        for (int ks = 0; ks < 4; ++ks)
            vfr[ks] = *(const short8*)(
                vT2b + ((size_t)(t * 4 + ks) * 128 + (w * 16 + n16)) * 32 + quad * 8);
        // QK: wave w rows i0+w*16..+15 x 64 j
        f32x4 dj[4];
        #pragma unroll
        for (int jc = 0; jc < 4; ++jc) {
            f32x4 d = {0.f, 0.f, 0.f, 0.f};
            #pragma unroll
            for (int c = 0; c < 4; ++c) {
                const short8 vf = *(const short8*)(
                    &vj[(jc * 16 + n16) * 128 + (((c * 4 + quad) ^ r8) * 8)]);
                d = mfma16(qa[c], vf, d);
            }
            dj[jc] = d;
        }
        const float linv[4] = {1.0f / (s0.x + s1.x), 1.0f / (s0.y + s1.y),
                               1.0f / (s0.z + s1.z), 1.0f / (s0.w + s1.w)};
        if (t < 15) {  // prefetch next iter q-frags + l-partials
            const unsigned short* qn = qbb + (size_t)(i0 + 128 + w * 16 + n16) * D_ + quad * 8;
            #pragma unroll
            for (int c = 0; c < 4; ++c) qa[c] = *(const short8*)(qn + c * 32);
            s0 = ld4(lp0 + i0 + 128 + w * 16 + quad * 4);
            s1 = ld4(lp1 + i0 + 128 + w * 16 + quad * 4);
        }
        // e -> eF (fp32, chunk^quad swizzle) + aT (bf16 [j][i], granule^r8 swizzle)
        const int ilb = w * 16 + quad * 4;
        #pragma unroll
        for (int jc = 0; jc < 4; ++jc) {
            s16x4 aw;
            #pragma unroll
            for (int r = 0; r < 4; ++r) {
                const float e = __expf(dj[jc][r] * SCALE) * linv[r];
                eFp[(ilb + r) * 64 + ((jc ^ quad) * 16) + n16] = e;
                aw[r] = bf(e);
            }
            *(s16x4*)(&aTp[(jc * 16 + n16) * 128 +
                           (((w * 2 + (quad >> 1)) ^ r8) * 8) + (quad & 1) * 4]) = aw;
        }
        BAR();
        // attn stores: 4 rows x 256B contiguous per instruction, nontemporal
        #pragma unroll
        for (int c = 0; c < 4; ++c) {
            const int g = c * 512 + tid, row = g >> 4, j4 = g & 15;
            const int phys = (j4 >> 2) ^ ((row >> 2) & 3);
            const f32x4 tv = *(const f32x4*)(&eFp[row * 64 + phys * 16 + (g & 3) * 4]);
            __builtin_nontemporal_store(
                tv, (f32x4*)(ab + (size_t)(i0 + row) * L_ + j0 + j4 * 4));
        }
        // PV: out[j][d] += attn^T[j][i] v[i][d], 4 ksteps x 4 j-tiles
        #pragma unroll
        for (int ks = 0; ks < 4; ++ks)
            #pragma unroll
            for (int jc = 0; jc < 4; ++jc) {
                const short8 af = *(const short8*)(
                    &aTp[(jc * 16 + n16) * 128 + (((ks * 4 + quad) ^ r8) * 8)]);
                oacc[jc] = mfma16(af, vfr[ks], oacc[jc]);
            }
    }
    // D[row=j_local=jc*16+quad*4+r][col=d=w*16+n16]
    #pragma unroll
    for (int jc = 0; jc < 4; ++jc)
        #pragma unroll
        for (int r = 0; r < 4; ++r)
            __builtin_nontemporal_store(
                oacc[jc][r],
                out + ((size_t)b * L_ + j0 + jc * 16 + quad * 4 + r) * D_ + w * 16 + n16);
}

extern "C" void kernel_launch(void* const* d_in, const int* in_sizes, int n_in,
                              void* d_out, int out_size, void* d_ws, size_t ws_size,
                              hipStream_t stream) {
    const float* q = (const float*)d_in[0];
    // d_in[1] = k: unused by the reference (scores come from q and v).
    const float* v = (const float*)d_in[2];
    float* out  = (float*)d_out;
    float* attn = out + (size_t)B_ * L_ * D_;  // outputs concatenated: [out | attn]

    cvt_q_kernel<<<dim3(1024), 256, 0, stream>>>(q);
    vT_kernel<<<dim3(B_ * 32), 256, 0, stream>>>(v);
    lsum_kernel<<<dim3(B_ * 64), 256, 0, stream>>>();
    fused_kernel<<<dim3(B_ * 32), 512, 0, stream>>>(attn, out);

    (void)in_sizes; (void)n_in; (void)out_size; (void)d_ws; (void)ws_size;
}